// Round 1
// baseline (428.562 us; speedup 1.0000x reference)
//
#include <hip/hip_runtime.h>

// ChunkedSelfAttention (RoPE + per-chunk causal SDPA), MI355X gfx950.
// Strategy: flash-attention per (b,chunk,head,qtile); f16 hi/lo split MFMA
// (32x32x16) for near-fp32 accuracy; RoPE fused (table in d_ws).

typedef __attribute__((ext_vector_type(2)))  float     f32x2;
typedef __attribute__((ext_vector_type(4)))  float     f32x4;
typedef __attribute__((ext_vector_type(16))) float     f32x16;
typedef __attribute__((ext_vector_type(8)))  _Float16  f16x8;
typedef unsigned int   u32;
typedef unsigned short u16;
typedef __attribute__((ext_vector_type(2))) unsigned int u32x2;

#define MFMA(a, b, c) __builtin_amdgcn_mfma_f32_32x32x16_f16(a, b, c, 0, 0, 0)

constexpr int Bb = 4, Ll = 4096, Hh = 16, Dd = 128;
// scale(1/sqrt(128)) * log2(e): softmax done in base-2 (exp2) domain.
constexpr float QSCALE = 0.08838834764831845f * 1.4426950408889634f;

// ---- LDS layout (bytes) ----
// KH [64][136] f16, KL same; VTH [128][72] f16 (V transposed), VTL same;
// P  per-wave [32][72] f16.
#define KH_OFF   0
#define KL_OFF   17408
#define VTH_OFF  34816
#define VTL_OFF  53248
#define P_OFF    71680
#define SMEM_SZ  108544

// ---- alias-safe load/store helpers (memcpy folds to ds/global vector ops) ----
__device__ __forceinline__ f16x8 ld_f16x8(const void* p) { f16x8 v; __builtin_memcpy(&v, p, 16); return v; }
__device__ __forceinline__ f32x4 ld_f32x4(const void* p) { f32x4 v; __builtin_memcpy(&v, p, 16); return v; }
__device__ __forceinline__ f32x2 ld_f32x2(const void* p) { f32x2 v; __builtin_memcpy(&v, p, 8);  return v; }
__device__ __forceinline__ void  st_u32 (void* p, u32 v)   { __builtin_memcpy(p, &v, 4); }
__device__ __forceinline__ void  st_u32x2(void* p, u32x2 v){ __builtin_memcpy(p, &v, 8); }

__device__ __forceinline__ u32 packh(_Float16 a, _Float16 b) {
  return (u32)__builtin_bit_cast(u16, a) | ((u32)__builtin_bit_cast(u16, b) << 16);
}
// split fp32 -> f16 hi + f16 lo (residual), two values packed per u32
__device__ __forceinline__ void split2(float a, float b, u32& hp, u32& lp) {
  _Float16 ha = (_Float16)a, hb = (_Float16)b;
  _Float16 la = (_Float16)(a - (float)ha), lb = (_Float16)(b - (float)hb);
  hp = packh(ha, hb);
  lp = packh(la, lb);
}

// ---- cos/sin table: tab[t*64+hid] = {cos, sin} of ang = (t+start)*inv_freq ----
// Mirrors reference fp32 op order: invf = expf(hid * (-ln(1e4)/64)); ang = pos*invf.
__global__ void rope_table_k(const int* __restrict__ startp, float* __restrict__ tab) {
  int idx = blockIdx.x * 256 + threadIdx.x;         // 4096*64 entries
  int t = idx >> 6, hid = idx & 63;
  float a = (float)hid * (-0.14391156831212878f);
  float invf = expf(a);
  float ang = (float)(t + startp[0]) * invf;
  tab[2 * idx]     = cosf(ang);
  tab[2 * idx + 1] = sinf(ang);
}

__global__ __launch_bounds__(512, 2)
void chunked_attn_k(const float* __restrict__ Qg, const float* __restrict__ Kg,
                    const float* __restrict__ Vg, float* __restrict__ Og,
                    const float* __restrict__ tab) {
  __shared__ __align__(16) unsigned char smem[SMEM_SZ];

  const int bx  = blockIdx.x;
  const int qi  = 3 - (bx & 3);          // q-tile (heavy tiles first)
  const int h   = (bx >> 2) & 15;
  const int c   = (bx >> 6) & 3;
  const int b   = bx >> 8;
  const int tid = threadIdx.x;
  const int w   = tid >> 6;              // wave 0..7
  const int lane= tid & 63;
  const int l31 = lane & 31;
  const int lg2 = lane >> 5;

  const size_t cbase = (size_t)(b * Ll + c * 1024);   // token base of this chunk
  // row pointer helper offsets: X + ((cbase+tt)*16 + h)*128
  const size_t hoff = (size_t)h * 128;

  // ---------- Q prologue: load 32 q-rows/wave into registers, rope+scale+split ----------
  const int qrow = qi * 256 + w * 32 + l31;           // chunk-local q row of this lane's column
  const float* qbase = Qg + ((cbase + qrow) * 16) * 128 + hoff;

  float xq[8][8];
  #pragma unroll
  for (int ds = 0; ds < 8; ++ds) {
    const float* p = qbase + ds * 16 + lg2 * 8;
    f32x4 v0 = ld_f32x4(p);
    f32x4 v1 = ld_f32x4(p + 4);
    xq[ds][0]=v0.x; xq[ds][1]=v0.y; xq[ds][2]=v0.z; xq[ds][3]=v0.w;
    xq[ds][4]=v1.x; xq[ds][5]=v1.y; xq[ds][6]=v1.z; xq[ds][7]=v1.w;
  }
  {
    const float* trow = tab + (size_t)(cbase % ((size_t)Bb*Ll) , 0) ;  // placeholder avoided below
  }
  const float* trowq = tab + (size_t)(c * 1024 + qrow) * 128 + lg2 * 16;
  #pragma unroll
  for (int ds = 0; ds < 4; ++ds) {
    #pragma unroll
    for (int i2 = 0; i2 < 4; ++i2) {
      f32x4 cs = ld_f32x4(trowq + ds * 32 + i2 * 4);  // c0,s0,c1,s1
      int i0 = 2 * i2;
      float a0 = xq[ds][i0],     b0 = xq[ds + 4][i0];
      xq[ds][i0]     = a0 * cs.x - b0 * cs.y;
      xq[ds + 4][i0] = b0 * cs.x + a0 * cs.y;
      float a1 = xq[ds][i0 + 1], b1 = xq[ds + 4][i0 + 1];
      xq[ds][i0 + 1]     = a1 * cs.z - b1 * cs.w;
      xq[ds + 4][i0 + 1] = b1 * cs.z + a1 * cs.w;
    }
  }
  f16x8 qh[8], ql[8];
  #pragma unroll
  for (int ds = 0; ds < 8; ++ds) {
    #pragma unroll
    for (int i = 0; i < 8; ++i) {
      float sv = xq[ds][i] * QSCALE;
      _Float16 hh = (_Float16)sv;
      qh[ds][i] = hh;
      ql[ds][i] = (_Float16)(sv - (float)hh);
    }
  }

  // ---------- state ----------
  f32x16 O[4];
  #pragma unroll
  for (int n = 0; n < 4; ++n) O[n] = (f32x16)0.0f;
  float m2 = -1e30f;      // running max (base-2 domain)
  float lsum = 0.0f;      // running denom
  const int jmax   = 4 * qi + (w >> 1);  // last kv tile this wave touches
  const int ntiles = 4 * (qi + 1);

  u32* KHu  = (u32*)(smem + KH_OFF);
  u32* KLu  = (u32*)(smem + KL_OFF);
  u32* VTHu = (u32*)(smem + VTH_OFF);
  u32* VTLu = (u32*)(smem + VTL_OFF);
  const unsigned char* khb = smem + KH_OFF + (size_t)l31 * 272 + lg2 * 16;
  const unsigned char* klb = smem + KL_OFF + (size_t)l31 * 272 + lg2 * 16;
  const unsigned char* vhb = smem + VTH_OFF + (size_t)l31 * 144 + lg2 * 16;
  const unsigned char* vlb = smem + VTL_OFF + (size_t)l31 * 144 + lg2 * 16;
  unsigned char* pbw = smem + P_OFF + (size_t)w * 4608;            // this wave's P tile
  const unsigned char* pbr = pbw + (size_t)l31 * 144 + lg2 * 16;

  for (int j = 0; j < ntiles; ++j) {
    __syncthreads();   // previous tile's LDS reads done

    // ---- stage K (rope + split) : 64 rows x 64 d-pairs, 4 slots/thread ----
    #pragma unroll
    for (int it = 0; it < 4; ++it) {
      int s   = tid + it * 512;
      int kk  = s >> 5;         // 0..63
      int dh2 = s & 31;         // pair of half-dims (d = 2dh2, 2dh2+1)
      const float* kr = Kg + ((cbase + j * 64 + kk) * 16) * 128 + hoff + 2 * dh2;
      f32x2 a  = ld_f32x2(kr);
      f32x2 bb = ld_f32x2(kr + 64);
      f32x4 cs = ld_f32x4(tab + (size_t)(c * 1024 + j * 64 + kk) * 128 + 4 * dh2);
      float ar0 = a.x * cs.x - bb.x * cs.y;
      float br0 = bb.x * cs.x + a.x * cs.y;
      float ar1 = a.y * cs.z - bb.y * cs.w;
      float br1 = bb.y * cs.z + a.y * cs.w;
      u32 hp, lp;
      split2(ar0, ar1, hp, lp);
      st_u32(&KHu[kk * 68 + dh2], hp);  st_u32(&KLu[kk * 68 + dh2], lp);
      split2(br0, br1, hp, lp);
      st_u32(&KHu[kk * 68 + 32 + dh2], hp);  st_u32(&KLu[kk * 68 + 32 + dh2], lp);
    }
    // ---- stage V transposed (split only): VT[dv][k], 8 slots/thread ----
    #pragma unroll
    for (int it = 0; it < 8; ++it) {
      int s  = tid + it * 512;
      int dv = s & 127;
      int kp = s >> 7;          // 0..31 (k = 2kp, 2kp+1)
      const float* vr = Vg + ((cbase + j * 64 + 2 * kp) * 16) * 128 + hoff + dv;
      float va = vr[0];
      float vb = vr[2048];
      u32 hp, lp;
      split2(va, vb, hp, lp);
      st_u32(&VTHu[dv * 36 + kp], hp);  st_u32(&VTLu[dv * 36 + kp], lp);
    }
    __syncthreads();

    if (j > jmax) continue;     // fully-masked for this wave (barriers stay aligned)

    // ---- QK^T (swapped): S^T[k][q] += K . Q^T, 3-term f16 split ----
    f32x16 S0 = (f32x16)0.0f, S1 = (f32x16)0.0f;   // kt=0: k 0..31, kt=1: k 32..63
    #pragma unroll
    for (int ds = 0; ds < 8; ++ds) {
      f16x8 kh0 = ld_f16x8(khb + ds * 32);
      f16x8 kh1 = ld_f16x8(khb + 8704 + ds * 32);
      f16x8 kl0 = ld_f16x8(klb + ds * 32);
      f16x8 kl1 = ld_f16x8(klb + 8704 + ds * 32);
      S0 = MFMA(kh0, qh[ds], S0);
      S1 = MFMA(kh1, qh[ds], S1);
      S0 = MFMA(kh0, ql[ds], S0);
      S1 = MFMA(kh1, ql[ds], S1);
      S0 = MFMA(kl0, qh[ds], S0);
      S1 = MFMA(kl1, qh[ds], S1);
    }

    // ---- causal mask (only diagonal tile) ----
    if (j == jmax) {
      #pragma unroll
      for (int r = 0; r < 16; ++r) {
        int krow = (r & 3) + 8 * (r >> 2) + 4 * lg2;
        if (j * 64 + krow      > qrow) S0[r] = -1e30f;
        if (j * 64 + 32 + krow > qrow) S1[r] = -1e30f;
      }
    }

    // ---- online softmax (base-2). lane holds 32 k-values of column q=l31 ----
    float tm = S0[0];
    #pragma unroll
    for (int r = 0; r < 16; ++r) { tm = fmaxf(tm, S0[r]); tm = fmaxf(tm, S1[r]); }
    tm = fmaxf(tm, __shfl_xor(tm, 32));
    float m2n = fmaxf(m2, tm);
    float fac = exp2f(m2 - m2n);
    _Float16 p0h[16], p1h[16];
    float ps = 0.0f;
    #pragma unroll
    for (int r = 0; r < 16; ++r) {
      _Float16 pa = (_Float16)exp2f(S0[r] - m2n);
      _Float16 pb = (_Float16)exp2f(S1[r] - m2n);
      p0h[r] = pa; p1h[r] = pb;
      ps += (float)pa + (float)pb;       // denom from rounded weights (cancels P rounding)
    }
    ps += __shfl_xor(ps, 32);
    lsum = lsum * fac + ps;
    m2 = m2n;
    // rescale O rows by this row's factor (broadcast from lane holding that q)
    #pragma unroll
    for (int r = 0; r < 16; ++r) {
      int rq = (r & 3) + 8 * (r >> 2) + 4 * lg2;
      float fr = __shfl(fac, rq);
      O[0][r] *= fr; O[1][r] *= fr; O[2][r] *= fr; O[3][r] *= fr;
    }

    // ---- write P tile [q][k] f16 (wave-private, no barrier needed) ----
    {
      u32* Pu = (u32*)pbw;
      #pragma unroll
      for (int rg = 0; rg < 4; ++rg) {
        u32x2 w0, w1;
        w0.x = packh(p0h[4 * rg + 0], p0h[4 * rg + 1]);
        w0.y = packh(p0h[4 * rg + 2], p0h[4 * rg + 3]);
        w1.x = packh(p1h[4 * rg + 0], p1h[4 * rg + 1]);
        w1.y = packh(p1h[4 * rg + 2], p1h[4 * rg + 3]);
        int base0 = l31 * 36 + 2 * lg2 + 4 * rg;       // kt=0
        st_u32x2(&Pu[base0], w0);
        st_u32x2(&Pu[base0 + 16], w1);                 // kt=1 (+32 f16 = +16 u32)
      }
    }

    // ---- PV: O[q][dv] += P . V  (P f16, V split hi/lo) ----
    #pragma unroll
    for (int ks = 0; ks < 4; ++ks) {
      f16x8 pa = ld_f16x8(pbr + ks * 32);
      #pragma unroll
      for (int n = 0; n < 4; ++n) {
        f16x8 vh = ld_f16x8(vhb + (size_t)n * 4608 + ks * 32);
        O[n] = MFMA(pa, vh, O[n]);
      }
      #pragma unroll
      for (int n = 0; n < 4; ++n) {
        f16x8 vl = ld_f16x8(vlb + (size_t)n * 4608 + ks * 32);
        O[n] = MFMA(pa, vl, O[n]);
      }
    }
  }

  // ---------- epilogue: divide by denom, store ----------
  float inv = 1.0f / lsum;
  #pragma unroll
  for (int r = 0; r < 16; ++r) {
    int rq = (r & 3) + 8 * (r >> 2) + 4 * lg2;
    float fi = __shfl(inv, rq);
    int tt = qi * 256 + w * 32 + rq;
    float* orow = Og + ((cbase + tt) * 16) * 128 + hoff + l31;
    orow[0]  = O[0][r] * fi;
    orow[32] = O[1][r] * fi;
    orow[64] = O[2][r] * fi;
    orow[96] = O[3][r] * fi;
  }
}

extern "C" void kernel_launch(void* const* d_in, const int* in_sizes, int n_in,
                              void* d_out, int out_size, void* d_ws, size_t ws_size,
                              hipStream_t stream) {
  const float* q = (const float*)d_in[0];
  const float* k = (const float*)d_in[1];
  const float* v = (const float*)d_in[2];
  const int* start = (const int*)d_in[3];
  float* out = (float*)d_out;
  float* tab = (float*)d_ws;     // 4096*64*2 floats = 2 MB

  rope_table_k<<<dim3(1024), dim3(256), 0, stream>>>(start, tab);
  chunked_attn_k<<<dim3(1024), dim3(512), 0, stream>>>(q, k, v, out, tab);
}